// Round 1
// baseline (76325.983 us; speedup 1.0000x reference)
//
#include <hip/hip_runtime.h>
#include <math.h>

#define HID   512
#define BATCH 512
#define TIN   512
#define TOUT  128

// Numerically-stable sigmoid matching jax.nn.sigmoid
__device__ __forceinline__ float stable_sigmoid(float x) {
    if (x >= 0.0f) {
        float e = expf(-x);
        return 1.0f / (1.0f + e);
    } else {
        float e = expf(x);
        return e / (1.0f + e);
    }
}

// One LSTM time step (encoder or decoder), fused GEMM + gates (+ decoder projection).
//
// Layouts (all fp32):
//   h:  hT[k][b]   (HID x BATCH)  -- transposed so lane=batch loads coalesce
//   c:  cT[j][b]   (HID x BATCH)  -- owned/updated in place by the block owning (j,b)
//   Whh row r = gate*HID + j, element k at Whh[r*HID + k]
//
// Grid: 256 blocks = 8 batch-groups (64 batches) x 32 j-groups (16 hidden).
// Block: 256 threads = 4 waves; lane = batch, wave w handles j = jg*16 + w*4 .. +3,
// all 4 gates -> 16 fp32 accumulators per lane.
__global__ __launch_bounds__(256) void lstm_step(
    const float* __restrict__ inputs,  // (BATCH, TIN) flattened; x source
    const float* __restrict__ Wih,     // (4*HID,)
    const float* __restrict__ Whh,     // (4*HID, HID)
    const float* __restrict__ bias,    // (4*HID,)
    const float* __restrict__ linW,    // (HID,)   decoder only
    const float* __restrict__ linb,    // (1,)     decoder only
    const float* __restrict__ h_in,    // hT
    float* __restrict__ h_out,         // hT (double buffer)
    float* __restrict__ c,             // cT
    float* __restrict__ out,           // (BATCH, TOUT) decoder only
    int t,
    int mode)                          // 0 = encoder, 1 = decoder
{
    const int lane = threadIdx.x & 63;
    const int wv   = __builtin_amdgcn_readfirstlane((int)(threadIdx.x >> 6));
    const int bg   = blockIdx.x & 7;    // batch group (8)
    const int jg   = blockIdx.x >> 3;   // hidden group (32)
    const int bidx = bg * 64 + lane;    // this lane's batch element
    const int j0   = jg * 16 + wv * 4;  // first of 4 hidden units for this wave

    // ---- determine x_t ----
    float x;
    if (mode == 0) {
        x = inputs[bidx * TIN + t];
    } else if (t == 0) {
        x = inputs[bidx * TIN + (TIN - 1)];   // x0 = inputs[:, -1, 0]
    } else {
        // x_t = out_{t-1} = h_in[.,b] dot linW + linb  (h_in is h after dec step t-1)
        float xa = 0.0f;
        for (int k = 0; k < HID; k += 4) {
            xa = fmaf(h_in[(k + 0) * BATCH + bidx], linW[k + 0], xa);
            xa = fmaf(h_in[(k + 1) * BATCH + bidx], linW[k + 1], xa);
            xa = fmaf(h_in[(k + 2) * BATCH + bidx], linW[k + 2], xa);
            xa = fmaf(h_in[(k + 3) * BATCH + bidx], linW[k + 3], xa);
        }
        x = xa + linb[0];
        // exactly one j-group writes out_{t-1}; all waves hold the same value, use wave 0
        if (jg == 0 && threadIdx.x < 64) {
            out[bidx * TOUT + (t - 1)] = x;
        }
    }

    // ---- z = bias + x*Wih + h @ Whh^T, 16 accumulators (4 gates x 4 j) ----
    float acc[4][4];
    #pragma unroll
    for (int g = 0; g < 4; ++g)
        #pragma unroll
        for (int jj = 0; jj < 4; ++jj) {
            int r = g * HID + j0 + jj;
            acc[g][jj] = fmaf(x, Wih[r], bias[r]);
        }

    for (int k = 0; k < HID; k += 4) {
        float hk0 = h_in[(k + 0) * BATCH + bidx];
        float hk1 = h_in[(k + 1) * BATCH + bidx];
        float hk2 = h_in[(k + 2) * BATCH + bidx];
        float hk3 = h_in[(k + 3) * BATCH + bidx];
        #pragma unroll
        for (int g = 0; g < 4; ++g) {
            #pragma unroll
            for (int jj = 0; jj < 4; ++jj) {
                const float* wrow = Whh + (g * HID + j0 + jj) * HID + k;
                float a = acc[g][jj];
                a = fmaf(hk0, wrow[0], a);
                a = fmaf(hk1, wrow[1], a);
                a = fmaf(hk2, wrow[2], a);
                a = fmaf(hk3, wrow[3], a);
                acc[g][jj] = a;
            }
        }
    }

    // ---- gates: i,f,g,o = z rows [0..512), [512..1024), [1024..1536), [1536..2048) ----
    #pragma unroll
    for (int jj = 0; jj < 4; ++jj) {
        int j = j0 + jj;
        float i_ = stable_sigmoid(acc[0][jj]);
        float f_ = stable_sigmoid(acc[1][jj]);
        float g_ = tanhf(acc[2][jj]);
        float o_ = stable_sigmoid(acc[3][jj]);
        float cv = c[j * BATCH + bidx];
        cv = f_ * cv + i_ * g_;
        c[j * BATCH + bidx] = cv;
        h_out[j * BATCH + bidx] = o_ * tanhf(cv);
    }
}

// Final projection: out[:, TOUT-1] = h dot linW + linb (h after last decoder step)
__global__ __launch_bounds__(256) void proj_final(
    const float* __restrict__ h_in,
    const float* __restrict__ linW,
    const float* __restrict__ linb,
    float* __restrict__ out)
{
    int bidx = blockIdx.x * 256 + threadIdx.x;   // grid 2 x 256 = 512 batches
    float xa = 0.0f;
    for (int k = 0; k < HID; k += 4) {
        xa = fmaf(h_in[(k + 0) * BATCH + bidx], linW[k + 0], xa);
        xa = fmaf(h_in[(k + 1) * BATCH + bidx], linW[k + 1], xa);
        xa = fmaf(h_in[(k + 2) * BATCH + bidx], linW[k + 2], xa);
        xa = fmaf(h_in[(k + 3) * BATCH + bidx], linW[k + 3], xa);
    }
    out[bidx * TOUT + (TOUT - 1)] = xa + linb[0];
}

extern "C" void kernel_launch(void* const* d_in, const int* in_sizes, int n_in,
                              void* d_out, int out_size, void* d_ws, size_t ws_size,
                              hipStream_t stream) {
    const float* inputs  = (const float*)d_in[0];
    // d_in[1] = targets (unused, teacher_forcing_ratio == 0)
    const float* enc_Wih = (const float*)d_in[2];
    const float* enc_Whh = (const float*)d_in[3];
    const float* enc_b   = (const float*)d_in[4];
    const float* dec_Wih = (const float*)d_in[5];
    const float* dec_Whh = (const float*)d_in[6];
    const float* dec_b   = (const float*)d_in[7];
    const float* lin_W   = (const float*)d_in[8];
    const float* lin_b   = (const float*)d_in[9];
    float* out = (float*)d_out;

    float* hA = (float*)d_ws;                  // hT double buffer A (1 MB)
    float* hB = hA + HID * BATCH;              // hT double buffer B (1 MB)
    float* cT = hB + HID * BATCH;              // cT (1 MB)

    // h0 = 0, c0 = 0 (ws is poisoned 0xAA before every call)
    hipMemsetAsync(hA, 0, HID * BATCH * sizeof(float), stream);
    hipMemsetAsync(cT, 0, HID * BATCH * sizeof(float), stream);

    float* hin  = hA;
    float* hout = hB;

    for (int t = 0; t < TIN; ++t) {
        lstm_step<<<256, 256, 0, stream>>>(inputs, enc_Wih, enc_Whh, enc_b,
                                           nullptr, nullptr, hin, hout, cT,
                                           nullptr, t, 0);
        float* tmp = hin; hin = hout; hout = tmp;
    }
    for (int t = 0; t < TOUT; ++t) {
        lstm_step<<<256, 256, 0, stream>>>(inputs, dec_Wih, dec_Whh, dec_b,
                                           lin_W, lin_b, hin, hout, cT,
                                           out, t, 1);
        float* tmp = hin; hin = hout; hout = tmp;
    }
    proj_final<<<2, 256, 0, stream>>>(hin, lin_W, lin_b, out);
}

// Round 2
// 17599.750 us; speedup vs baseline: 4.3368x; 4.3368x over previous
//
#include <hip/hip_runtime.h>
#include <math.h>

#define HID   512
#define BATCH 512
#define TIN   512
#define TOUT  128
#define FOUR_H 2048

typedef __bf16 bf16x8 __attribute__((ext_vector_type(8)));
typedef float floatx4 __attribute__((ext_vector_type(4)));

__device__ __forceinline__ float stable_sigmoid(float x) {
    if (x >= 0.0f) {
        float e = expf(-x);
        return 1.0f / (1.0f + e);
    } else {
        float e = expf(x);
        return e / (1.0f + e);
    }
}

// ---------- prep: pack Whh (4H x H fp32, gate-major rows) into m' = 4*j + g
// ---------- order, split into bf16 hi/lo planes.
__global__ __launch_bounds__(256) void pack_w(
    const float* __restrict__ W,    // [2048][512] fp32, row r = g*512 + j
    __bf16* __restrict__ outHi,     // [2048][512] bf16, row m' = 4*j + g
    __bf16* __restrict__ outLo)
{
    int tid = blockIdx.x * 256 + threadIdx.x;     // 131072 threads
    int mp  = tid >> 6;                           // m' in [0,2048)
    int kg  = (tid & 63) * 8;                     // k group of 8
    int g   = mp & 3;
    int j   = mp >> 2;
    int r   = g * HID + j;
    const float* src = W + (size_t)r * HID + kg;
    __bf16* dh = outHi + (size_t)mp * HID + kg;
    __bf16* dl = outLo + (size_t)mp * HID + kg;
    #pragma unroll
    for (int i = 0; i < 8; ++i) {
        float x = src[i];
        __bf16 hi = (__bf16)x;
        float rem = x - (float)hi;
        dh[i] = hi;
        dl[i] = (__bf16)rem;
    }
}

// pack Wih (2048) and bias (2048) into m' order, fp32
__global__ __launch_bounds__(256) void pack_v(
    const float* __restrict__ Wih, const float* __restrict__ b,
    float* __restrict__ WihP, float* __restrict__ bP)
{
    int mp = blockIdx.x * 256 + threadIdx.x;      // 2048 threads
    int g  = mp & 3;
    int j  = mp >> 2;
    int r  = g * HID + j;
    WihP[mp] = Wih[r];
    bP[mp]   = b[r];
}

// ---------- fused LSTM step: Z = W'.(Hhi+Hlo) via 3-product bf16 split MFMA,
// then gates + c update + h split-write. Grid (32, 8) x 256 threads.
// Block tile: 64 m' x 64 b. Wave w: m' rows [w*16, w*16+16) x all 64 b.
__global__ __launch_bounds__(256, 1) void lstm_step_mfma(
    const __bf16* __restrict__ Ahi,    // [2048][512] packed weights hi
    const __bf16* __restrict__ Alo,    // lo
    const float* __restrict__ WihP,    // [2048] packed
    const float* __restrict__ biasP,   // [2048] packed
    const float* __restrict__ inputs,  // [512][512]
    const float* __restrict__ xfeed,   // [512] decoder feedback
    const __bf16* __restrict__ hin_hi, // [b][k] = [512][512]
    const __bf16* __restrict__ hin_lo,
    __bf16* __restrict__ hout_hi,
    __bf16* __restrict__ hout_lo,
    float* __restrict__ cT,            // [j][b] fp32
    int t, int mode)                   // mode 0 = encoder, 1 = decoder
{
    const int lane = threadIdx.x & 63;
    const int w    = threadIdx.x >> 6;
    const int lr   = lane & 15;     // row-in-16 (A) / col (B, C)
    const int lq   = lane >> 4;     // quad
    const int mbase = blockIdx.x * 64 + w * 16;   // first m' row of this wave
    const int nbase = blockIdx.y * 64;            // first b of this block

    // fragment base pointers
    const __bf16* aHi = Ahi + (size_t)(mbase + lr) * HID + lq * 8;
    const __bf16* aLo = Alo + (size_t)(mbase + lr) * HID + lq * 8;
    const __bf16* bH[4];
    const __bf16* bL[4];
    #pragma unroll
    for (int nt = 0; nt < 4; ++nt) {
        int bn = nbase + nt * 16 + lr;
        bH[nt] = hin_hi + (size_t)bn * HID + lq * 8;
        bL[nt] = hin_lo + (size_t)bn * HID + lq * 8;
    }

    floatx4 acc0 = {0.f, 0.f, 0.f, 0.f};
    floatx4 acc1 = {0.f, 0.f, 0.f, 0.f};
    floatx4 acc2 = {0.f, 0.f, 0.f, 0.f};
    floatx4 acc3 = {0.f, 0.f, 0.f, 0.f};

    #pragma unroll
    for (int kc = 0; kc < HID; kc += 32) {
        bf16x8 ah = *(const bf16x8*)(aHi + kc);
        bf16x8 al = *(const bf16x8*)(aLo + kc);
        bf16x8 bh0 = *(const bf16x8*)(bH[0] + kc);
        bf16x8 bl0 = *(const bf16x8*)(bL[0] + kc);
        bf16x8 bh1 = *(const bf16x8*)(bH[1] + kc);
        bf16x8 bl1 = *(const bf16x8*)(bL[1] + kc);
        bf16x8 bh2 = *(const bf16x8*)(bH[2] + kc);
        bf16x8 bl2 = *(const bf16x8*)(bL[2] + kc);
        bf16x8 bh3 = *(const bf16x8*)(bH[3] + kc);
        bf16x8 bl3 = *(const bf16x8*)(bL[3] + kc);

        acc0 = __builtin_amdgcn_mfma_f32_16x16x32_bf16(ah, bh0, acc0, 0, 0, 0);
        acc1 = __builtin_amdgcn_mfma_f32_16x16x32_bf16(ah, bh1, acc1, 0, 0, 0);
        acc2 = __builtin_amdgcn_mfma_f32_16x16x32_bf16(ah, bh2, acc2, 0, 0, 0);
        acc3 = __builtin_amdgcn_mfma_f32_16x16x32_bf16(ah, bh3, acc3, 0, 0, 0);
        acc0 = __builtin_amdgcn_mfma_f32_16x16x32_bf16(al, bh0, acc0, 0, 0, 0);
        acc1 = __builtin_amdgcn_mfma_f32_16x16x32_bf16(al, bh1, acc1, 0, 0, 0);
        acc2 = __builtin_amdgcn_mfma_f32_16x16x32_bf16(al, bh2, acc2, 0, 0, 0);
        acc3 = __builtin_amdgcn_mfma_f32_16x16x32_bf16(al, bh3, acc3, 0, 0, 0);
        acc0 = __builtin_amdgcn_mfma_f32_16x16x32_bf16(ah, bl0, acc0, 0, 0, 0);
        acc1 = __builtin_amdgcn_mfma_f32_16x16x32_bf16(ah, bl1, acc1, 0, 0, 0);
        acc2 = __builtin_amdgcn_mfma_f32_16x16x32_bf16(ah, bl2, acc2, 0, 0, 0);
        acc3 = __builtin_amdgcn_mfma_f32_16x16x32_bf16(ah, bl3, acc3, 0, 0, 0);
    }

    // ---- epilogue: each lane holds gates i,f,g,o (regs 0..3) for one j, 4 b's
    const int m0 = mbase + lq * 4;          // first of lane's 4 m' rows (= 4*j)
    const int j  = m0 >> 2;
    const floatx4 wih4  = *(const floatx4*)(WihP + m0);
    const floatx4 bias4 = *(const floatx4*)(biasP + m0);

    floatx4 accs[4] = {acc0, acc1, acc2, acc3};
    #pragma unroll
    for (int nt = 0; nt < 4; ++nt) {
        int bn = nbase + nt * 16 + lr;
        float x;
        if (mode == 0) {
            x = inputs[(size_t)bn * TIN + t];
        } else if (t == 0) {
            x = inputs[(size_t)bn * TIN + (TIN - 1)];
        } else {
            x = xfeed[bn];
        }
        float zi = accs[nt][0] + bias4[0] + x * wih4[0];
        float zf = accs[nt][1] + bias4[1] + x * wih4[1];
        float zg = accs[nt][2] + bias4[2] + x * wih4[2];
        float zo = accs[nt][3] + bias4[3] + x * wih4[3];
        float i_ = stable_sigmoid(zi);
        float f_ = stable_sigmoid(zf);
        float g_ = tanhf(zg);
        float o_ = stable_sigmoid(zo);
        size_t cidx = (size_t)j * BATCH + bn;
        float cv = cT[cidx];
        cv = f_ * cv + i_ * g_;
        cT[cidx] = cv;
        float hv = o_ * tanhf(cv);
        __bf16 hh = (__bf16)hv;
        float rem = hv - (float)hh;
        hout_hi[(size_t)bn * HID + j] = hh;
        hout_lo[(size_t)bn * HID + j] = (__bf16)rem;
    }
}

// ---------- decoder projection: out[:,t] = xfeed = h . linW + linb
__global__ __launch_bounds__(64) void proj(
    const __bf16* __restrict__ h_hi, const __bf16* __restrict__ h_lo,
    const float* __restrict__ linW, const float* __restrict__ linb,
    float* __restrict__ out, float* __restrict__ xfeed, int t)
{
    int b = blockIdx.x * 64 + threadIdx.x;   // grid 8 x 64
    const __bf16* ph = h_hi + (size_t)b * HID;
    const __bf16* pl = h_lo + (size_t)b * HID;
    float s = 0.0f;
    for (int k = 0; k < HID; k += 8) {
        bf16x8 vh = *(const bf16x8*)(ph + k);
        bf16x8 vl = *(const bf16x8*)(pl + k);
        #pragma unroll
        for (int i = 0; i < 8; ++i) {
            s = fmaf((float)vh[i] + (float)vl[i], linW[k + i], s);
        }
    }
    s += linb[0];
    out[(size_t)b * TOUT + t] = s;
    xfeed[b] = s;
}

extern "C" void kernel_launch(void* const* d_in, const int* in_sizes, int n_in,
                              void* d_out, int out_size, void* d_ws, size_t ws_size,
                              hipStream_t stream) {
    const float* inputs  = (const float*)d_in[0];
    const float* enc_Wih = (const float*)d_in[2];
    const float* enc_Whh = (const float*)d_in[3];
    const float* enc_b   = (const float*)d_in[4];
    const float* dec_Wih = (const float*)d_in[5];
    const float* dec_Whh = (const float*)d_in[6];
    const float* dec_b   = (const float*)d_in[7];
    const float* lin_W   = (const float*)d_in[8];
    const float* lin_b   = (const float*)d_in[9];
    float* out = (float*)d_out;

    char* ws = (char*)d_ws;
    const size_t SZ_A = (size_t)FOUR_H * HID * sizeof(__bf16);  // 2 MB
    const size_t SZ_V = (size_t)FOUR_H * sizeof(float);         // 8 KB
    const size_t SZ_H = (size_t)BATCH * HID * sizeof(__bf16);   // 512 KB
    const size_t SZ_C = (size_t)BATCH * HID * sizeof(float);    // 1 MB

    __bf16* AencHi = (__bf16*)(ws);
    __bf16* AencLo = (__bf16*)(ws + SZ_A);
    __bf16* AdecHi = (__bf16*)(ws + 2 * SZ_A);
    __bf16* AdecLo = (__bf16*)(ws + 3 * SZ_A);
    char* p = ws + 4 * SZ_A;
    float* WihPenc  = (float*)(p);            p += SZ_V;
    float* biasPenc = (float*)(p);            p += SZ_V;
    float* WihPdec  = (float*)(p);            p += SZ_V;
    float* biasPdec = (float*)(p);            p += SZ_V;
    __bf16* hA_hi = (__bf16*)(p);             p += SZ_H;
    __bf16* hA_lo = (__bf16*)(p);             p += SZ_H;
    __bf16* hB_hi = (__bf16*)(p);             p += SZ_H;
    __bf16* hB_lo = (__bf16*)(p);             p += SZ_H;
    float* cT    = (float*)(p);               p += SZ_C;
    float* xfeed = (float*)(p);               p += BATCH * sizeof(float);

    // ---- prep: pack weights, zero state ----
    pack_w<<<512, 256, 0, stream>>>(enc_Whh, AencHi, AencLo);
    pack_w<<<512, 256, 0, stream>>>(dec_Whh, AdecHi, AdecLo);
    pack_v<<<8, 256, 0, stream>>>(enc_Wih, enc_b, WihPenc, biasPenc);
    pack_v<<<8, 256, 0, stream>>>(dec_Wih, dec_b, WihPdec, biasPdec);
    hipMemsetAsync(hA_hi, 0, SZ_H, stream);
    hipMemsetAsync(hA_lo, 0, SZ_H, stream);
    hipMemsetAsync(cT, 0, SZ_C, stream);

    __bf16 *hin_hi = hA_hi, *hin_lo = hA_lo, *hout_hi = hB_hi, *hout_lo = hB_lo;
    dim3 grid(32, 8);

    for (int t = 0; t < TIN; ++t) {
        lstm_step_mfma<<<grid, 256, 0, stream>>>(
            AencHi, AencLo, WihPenc, biasPenc, inputs, xfeed,
            hin_hi, hin_lo, hout_hi, hout_lo, cT, t, 0);
        __bf16* tmp;
        tmp = hin_hi; hin_hi = hout_hi; hout_hi = tmp;
        tmp = hin_lo; hin_lo = hout_lo; hout_lo = tmp;
    }
    for (int t = 0; t < TOUT; ++t) {
        lstm_step_mfma<<<grid, 256, 0, stream>>>(
            AdecHi, AdecLo, WihPdec, biasPdec, inputs, xfeed,
            hin_hi, hin_lo, hout_hi, hout_lo, cT, t, 1);
        __bf16* tmp;
        tmp = hin_hi; hin_hi = hout_hi; hout_hi = tmp;
        tmp = hin_lo; hin_lo = hout_lo; hout_lo = tmp;
        proj<<<8, 64, 0, stream>>>(hin_hi, hin_lo, lin_W, lin_b, out, xfeed, t);
    }
}